// Round 21
// baseline (90.225 us; speedup 1.0000x reference)
//
#include <hip/hip_runtime.h>
#include <hip/hip_bf16.h>
#include <hip/hip_fp8.h>
#include <stdint.h>

// Problem constants (fixed by reference): B=2048, D=256, Vg=2, Vt=4 (only j<2 used), T=0.2
#define TB 2048
#define TD 256

// A/B DIAGNOSTIC: mainA (R10 2-pair) vs mainB (R18 1-pair), both REP=2 so both
// surface in rocprof top-5 with counters. mainA feeds the real output.
#define REP_MAIN 2

typedef long long                                         fp8x8;   // 8 fp8 = 2 VGPR
typedef __attribute__((ext_vector_type(8)))  int          int8v;   // 32 fp8 = 8 VGPR
typedef __attribute__((ext_vector_type(16))) float        f32x16;

union frag32 { fp8x8 g[4]; int8v v; };   // 4 x 8B granules = one 32x32x64 operand

#define SQRT5 2.23606797749979f
#define SCALE1 0x7F               // E8M0: 2^(127-127) = 1.0

// ---------------------------------------------------------------------------
// Kernel 1: prep (== R10). <=2us.
// ---------------------------------------------------------------------------
__global__ __launch_bounds__(256) void nnclr_prep(const float* __restrict__ proj,
                                                  const float* __restrict__ pred,
                                                  unsigned char* __restrict__ pq2) {
    const int grp = blockIdx.x, v = blockIdx.y, t = threadIdx.x;
    __shared__ float rowbuf[32][260];
    __shared__ float scales[32];

    #pragma unroll
    for (int it = 0; it < 8; ++it) {
        const int f = it * 256 + t;
        const int m = f >> 6, q = f & 63;
        const int b = grp * 32 + m;
        const float4* src = (v < 2) ? (const float4*)(proj + ((size_t)b * 2 + v) * TD)
                                    : (const float4*)(pred + ((size_t)b * 4 + (v - 2)) * TD);
        *(float4*)&rowbuf[m][q * 4] = src[q];
    }
    __syncthreads();
    {
        const int row = t >> 3, l8 = t & 7;
        float ss = 0.f;
        #pragma unroll
        for (int n = 0; n < 32; ++n) { const float y = rowbuf[row][l8 + 8 * n]; ss += y * y; }
        ss += __shfl_xor(ss, 1, 64);
        ss += __shfl_xor(ss, 2, 64);
        ss += __shfl_xor(ss, 4, 64);
        if (l8 == 0) scales[row] = SQRT5 / fmaxf(sqrtf(ss), 1e-12f);
    }
    __syncthreads();
    unsigned int* dst32 = (unsigned int*)(pq2 + (size_t)(v * 64 + grp) * 8192);
    #pragma unroll
    for (int it = 0; it < 8; ++it) {
        const int u = it * 256 + t;
        const int m = u >> 6, col = (u >> 1) & 31, e4 = u & 1;
        const float sc = scales[col];
        unsigned int w = 0;
        #pragma unroll
        for (int i = 0; i < 4; ++i) {
            const float y = rowbuf[col][m * 8 + 4 * e4 + i] * sc;
            const __hip_fp8_e4m3 f8(y);
            w |= ((unsigned int)f8.__x) << (8 * i);
        }
        dst32[u] = w;
    }
}

// ---------------------------------------------------------------------------
// Kernel 2A: R10 structure — BOTH i per block, B reused 2x. grid (64,4,2).
// Produces the REAL sPart/dPart. REP=2 (idempotent).
// ---------------------------------------------------------------------------
__global__ __launch_bounds__(256, 2) void nnclr_mainA(const unsigned char* __restrict__ pq2,
                                                      float* __restrict__ sPart,
                                                      float* __restrict__ dPart)
{
    const int rb = blockIdx.x, ch = blockIdx.y, j = blockIdx.z;
    const int tid = threadIdx.x, lane = tid & 63, wave = tid >> 6;
    const int cl = lane & 31, hk = lane >> 5;
    const int b0 = rb * 32;

    __shared__ float sArr[2][4][32];
    __shared__ float dArr[2][4][32];

    for (int rep = 0; rep < REP_MAIN; ++rep) {
        asm volatile("" ::: "memory");
        const fp8x8* P = (const fp8x8*)pq2;
        frag32 aF0[4], aF1[4];
        #pragma unroll
        for (int kb = 0; kb < 4; ++kb) {
            #pragma unroll
            for (int q = 0; q < 4; ++q) {
                const int g = 8 * kb + 4 * hk + q;
                aF0[kb].g[q] = P[((0 * 64 + rb) * 32 + g) * 32 + cl];
                aF1[kb].g[q] = P[((1 * 64 + rb) * 32 + g) * 32 + cl];
            }
        }
        float sAcc0[16], sAcc1[16];
        #pragma unroll
        for (int r = 0; r < 16; ++r) { sAcc0[r] = 0.f; sAcc1[r] = 0.f; }
        float d0 = 0.f, d1 = 0.f;
        const int  rDiag    = (cl & 3) + 4 * (cl >> 3);
        const bool laneDiag = (((cl >> 2) & 1) == hk);
        const fp8x8* Bbase = P + (size_t)(2 + j) * 64 * 32 * 32;
        const int cg0 = ch * 16 + wave * 4;

        frag32 bf[2][4];
        #pragma unroll
        for (int kb = 0; kb < 4; ++kb)
            #pragma unroll
            for (int q = 0; q < 4; ++q)
                bf[0][kb].g[q] = Bbase[((size_t)cg0 * 32 + 8 * kb + 4 * hk + q) * 32 + cl];

        #pragma unroll
        for (int cgl = 0; cgl < 4; ++cgl) {
            const int cg = cg0 + cgl;
            if (cgl < 3) {
                #pragma unroll
                for (int kb = 0; kb < 4; ++kb)
                    #pragma unroll
                    for (int q = 0; q < 4; ++q)
                        bf[(cgl + 1) & 1][kb].g[q] =
                            Bbase[((size_t)(cg + 1) * 32 + 8 * kb + 4 * hk + q) * 32 + cl];
            }
            f32x16 acc0, acc1;
            #pragma unroll
            for (int r = 0; r < 16; ++r) { acc0[r] = 0.f; acc1[r] = 0.f; }
            #pragma unroll
            for (int kb = 0; kb < 4; ++kb) {
                acc0 = __builtin_amdgcn_mfma_scale_f32_32x32x64_f8f6f4(
                           aF0[kb].v, bf[cgl & 1][kb].v, acc0, 0, 0, 0, SCALE1, 0, SCALE1);
                acc1 = __builtin_amdgcn_mfma_scale_f32_32x32x64_f8f6f4(
                           aF1[kb].v, bf[cgl & 1][kb].v, acc1, 0, 0, 0, SCALE1, 0, SCALE1);
            }
            const bool diagCG = (cg == rb);
            #pragma unroll
            for (int r = 0; r < 16; ++r) {
                const float v0 = acc0[r], v1 = acc1[r];
                sAcc0[r] += __expf(v0 - 5.0f);
                sAcc1[r] += __expf(v1 - 5.0f);
                if (diagCG) {
                    const bool m = laneDiag && (r == rDiag);
                    d0 += m ? v0 : 0.f;
                    d1 += m ? v1 : 0.f;
                }
            }
        }
        #pragma unroll
        for (int r = 0; r < 16; ++r) {
            float s0 = sAcc0[r], s1 = sAcc1[r];
            #pragma unroll
            for (int msk = 1; msk < 32; msk <<= 1) {
                s0 += __shfl_xor(s0, msk, 64);
                s1 += __shfl_xor(s1, msk, 64);
            }
            sAcc0[r] = s0; sAcc1[r] = s1;
        }
        if (cl == 0) {
            #pragma unroll
            for (int r = 0; r < 16; ++r) {
                const int rowl = (r & 3) + 8 * (r >> 2) + 4 * hk;
                sArr[0][wave][rowl] = sAcc0[r];
                sArr[1][wave][rowl] = sAcc1[r];
            }
        }
        if (laneDiag) { dArr[0][wave][cl] = d0; dArr[1][wave][cl] = d1; }
        __syncthreads();
        if (tid < 64) {
            const int i = tid >> 5, row = tid & 31;
            float s = 0.f, d = 0.f;
            #pragma unroll
            for (int w = 0; w < 4; ++w) { s += sArr[i][w][row]; d += dArr[i][w][row]; }
            const int pair = i * 2 + j;
            const int b = b0 + row;
            sPart[((size_t)pair * TB + b) * 4 + ch] = s;
            dPart[((size_t)pair * TB + b) * 4 + ch] = d;
        }
        __syncthreads();
    }
}

// ---------------------------------------------------------------------------
// Kernel 2B: R18 structure — ONE pair per block. grid (64,4,4). Scratch out.
// ---------------------------------------------------------------------------
__global__ __launch_bounds__(256, 2) void nnclr_mainB(const unsigned char* __restrict__ pq2,
                                                      float* __restrict__ sOut,
                                                      float* __restrict__ dOut)
{
    const int rb = blockIdx.x, ch = blockIdx.y, pair = blockIdx.z;
    const int pi = pair >> 1, pj = pair & 1;
    const int tid = threadIdx.x, lane = tid & 63, wave = tid >> 6;
    const int cl = lane & 31, hk = lane >> 5;
    const int b0 = rb * 32;

    __shared__ float sArr[4][32];
    __shared__ float dArr[4][32];

    for (int rep = 0; rep < REP_MAIN; ++rep) {
        asm volatile("" ::: "memory");
        const fp8x8* P = (const fp8x8*)pq2;
        frag32 aF[4];
        #pragma unroll
        for (int kb = 0; kb < 4; ++kb)
            #pragma unroll
            for (int q = 0; q < 4; ++q)
                aF[kb].g[q] = P[((pi * 64 + rb) * 32 + 8 * kb + 4 * hk + q) * 32 + cl];

        float sAcc[16];
        #pragma unroll
        for (int r = 0; r < 16; ++r) sAcc[r] = 0.f;
        float d0 = 0.f;
        const int  rDiag    = (cl & 3) + 4 * (cl >> 3);
        const bool laneDiag = (((cl >> 2) & 1) == hk);
        const fp8x8* Bbase = P + (size_t)(2 + pj) * 64 * 32 * 32;
        const int cg0 = ch * 16 + wave * 4;

        #pragma unroll
        for (int cgl = 0; cgl < 4; ++cgl) {
            const int cg = cg0 + cgl;
            frag32 bf[4];
            #pragma unroll
            for (int kb = 0; kb < 4; ++kb)
                #pragma unroll
                for (int q = 0; q < 4; ++q)
                    bf[kb].g[q] = Bbase[((size_t)cg * 32 + 8 * kb + 4 * hk + q) * 32 + cl];
            f32x16 acc;
            #pragma unroll
            for (int r = 0; r < 16; ++r) acc[r] = 0.f;
            #pragma unroll
            for (int kb = 0; kb < 4; ++kb)
                acc = __builtin_amdgcn_mfma_scale_f32_32x32x64_f8f6f4(
                          aF[kb].v, bf[kb].v, acc, 0, 0, 0, SCALE1, 0, SCALE1);
            const bool diagCG = (cg == rb);
            #pragma unroll
            for (int r = 0; r < 16; ++r) {
                const float v0 = acc[r];
                sAcc[r] += __expf(v0 - 5.0f);
                if (diagCG) {
                    const bool m = laneDiag && (r == rDiag);
                    d0 += m ? v0 : 0.f;
                }
            }
        }
        #pragma unroll
        for (int r = 0; r < 16; ++r) {
            float s0 = sAcc[r];
            #pragma unroll
            for (int msk = 1; msk < 32; msk <<= 1) s0 += __shfl_xor(s0, msk, 64);
            sAcc[r] = s0;
        }
        if (cl == 0) {
            #pragma unroll
            for (int r = 0; r < 16; ++r) {
                const int rowl = (r & 3) + 8 * (r >> 2) + 4 * hk;
                sArr[wave][rowl] = sAcc[r];
            }
        }
        if (laneDiag) dArr[wave][cl] = d0;
        __syncthreads();
        if (tid < 32) {
            float s = 0.f, d = 0.f;
            #pragma unroll
            for (int w = 0; w < 4; ++w) { s += sArr[w][tid]; d += dArr[w][tid]; }
            const int b = b0 + tid;
            sOut[((size_t)pair * TB + b) * 4 + ch] = s;
            dOut[((size_t)pair * TB + b) * 4 + ch] = d;
        }
        __syncthreads();
    }
}

// ---------------------------------------------------------------------------
// Kernel 3: merged final (== R10). <=2.5us.
// ---------------------------------------------------------------------------
__global__ __launch_bounds__(1024) void nnclr_final(const float* __restrict__ sPart,
                                                    const float* __restrict__ dPart,
                                                    float* __restrict__ out) {
    const int tid = threadIdx.x;
    float acc[4] = {0.f, 0.f, 0.f, 0.f};
    #pragma unroll
    for (int k = 0; k < 8; ++k) {
        const int item = k * 1024 + tid;
        const float4 sv = ((const float4*)sPart)[item];
        const float4 dv = ((const float4*)dPart)[item];
        const float s = (sv.x + sv.y) + (sv.z + sv.w);
        const float d = (dv.x + dv.y) + (dv.z + dv.w);
        acc[k >> 1] += 5.0f + logf(s) - d;
    }
    __shared__ float red[16][4];
    const int lane = tid & 63, wave = tid >> 6;
    #pragma unroll
    for (int p = 0; p < 4; ++p) {
        #pragma unroll
        for (int m = 1; m < 64; m <<= 1) acc[p] += __shfl_xor(acc[p], m, 64);
    }
    if (lane == 0) {
        #pragma unroll
        for (int p = 0; p < 4; ++p) red[wave][p] = acc[p];
    }
    __syncthreads();
    if (tid == 0) {
        float L[4];
        #pragma unroll
        for (int p = 0; p < 4; ++p) {
            float a = 0.f;
            for (int w = 0; w < 16; ++w) a += red[w][p];
            L[p] = a / (float)TB;
        }
        const float gs = L[1] + L[2];
        const float ls = L[0] + L[1] + L[2] + L[3];
        out[0] = (gs + ls) / 6.0f;
        out[1] = gs * 0.5f;
        out[2] = ls * 0.25f;
    }
}

extern "C" void kernel_launch(void* const* d_in, const int* in_sizes, int n_in,
                              void* d_out, int out_size, void* d_ws, size_t ws_size,
                              hipStream_t stream) {
    const float* projected = (const float*)d_in[0];
    const float* predicted = (const float*)d_in[1];

    unsigned char* pq2 = (unsigned char*)d_ws;                          // 2 MB
    float* sPart = (float*)((char*)d_ws + 4u * 1024u * 1024u);          // 128 KB (real)
    float* dPart = sPart + (size_t)4 * TB * 4;                          // 128 KB (real)
    float* sScr  = dPart + (size_t)4 * TB * 4;                          // 128 KB (scratch)
    float* dScr  = sScr  + (size_t)4 * TB * 4;                          // 128 KB (scratch)
    float* out = (float*)d_out;

    dim3 gprep(64, 4);
    nnclr_prep<<<gprep, 256, 0, stream>>>(projected, predicted, pq2);
    dim3 gA(64, 4, 2);
    nnclr_mainA<<<gA, 256, 0, stream>>>(pq2, sPart, dPart);   // real output
    dim3 gB(64, 4, 4);
    nnclr_mainB<<<gB, 256, 0, stream>>>(pq2, sScr, dScr);     // A/B scratch
    nnclr_final<<<1, 1024, 0, stream>>>(sPart, dPart, out);
}

// Round 25
// 32.447 us; speedup vs baseline: 2.7807x; 2.7807x over previous
//
#include <hip/hip_runtime.h>
#include <hip/hip_bf16.h>
#include <hip/hip_fp8.h>
#include <stdint.h>

// Problem constants (fixed by reference): B=2048, D=256, Vg=2, Vt=4 (only j<2 used), T=0.2
#define TB 2048
#define TD 256

typedef long long                                         fp8x8;   // 8 fp8 = 2 VGPR
typedef __attribute__((ext_vector_type(8)))  int          int8v;   // 32 fp8 = 8 VGPR
typedef __attribute__((ext_vector_type(16))) float        f32x16;

union frag32 { fp8x8 g[4]; int8v v; };   // 4 x 8B granules = one 32x32x64 operand

#define SQRT5 2.23606797749979f   // fold sqrt(1/T)=sqrt(5) into BOTH normalized operands
#define SCALE1 0x7F               // E8M0: 2^(127-127) = 1.0

// ---------------------------------------------------------------------------
// Kernel 1: normalize rows, scale by sqrt(5), cast fp8-e4m3 (OCP), write in
// MFMA fragment order: pq2[v][grp][g][col] of 8B granules. (== R10, ~2us)
// ---------------------------------------------------------------------------
__global__ __launch_bounds__(256) void nnclr_prep(const float* __restrict__ proj,
                                                  const float* __restrict__ pred,
                                                  unsigned char* __restrict__ pq2) {
    const int grp = blockIdx.x, v = blockIdx.y, t = threadIdx.x;
    __shared__ float rowbuf[32][260];
    __shared__ float scales[32];

    #pragma unroll
    for (int it = 0; it < 8; ++it) {
        const int f = it * 256 + t;
        const int m = f >> 6, q = f & 63;
        const int b = grp * 32 + m;
        const float4* src = (v < 2) ? (const float4*)(proj + ((size_t)b * 2 + v) * TD)
                                    : (const float4*)(pred + ((size_t)b * 4 + (v - 2)) * TD);
        *(float4*)&rowbuf[m][q * 4] = src[q];
    }
    __syncthreads();
    {
        const int row = t >> 3, l8 = t & 7;
        float ss = 0.f;
        #pragma unroll
        for (int n = 0; n < 32; ++n) { const float y = rowbuf[row][l8 + 8 * n]; ss += y * y; }
        ss += __shfl_xor(ss, 1, 64);
        ss += __shfl_xor(ss, 2, 64);
        ss += __shfl_xor(ss, 4, 64);
        if (l8 == 0) scales[row] = SQRT5 / fmaxf(sqrtf(ss), 1e-12f);
    }
    __syncthreads();
    unsigned int* dst32 = (unsigned int*)(pq2 + (size_t)(v * 64 + grp) * 8192);
    #pragma unroll
    for (int it = 0; it < 8; ++it) {
        const int u = it * 256 + t;
        const int m = u >> 6, col = (u >> 1) & 31, e4 = u & 1;
        const float sc = scales[col];
        unsigned int w = 0;
        #pragma unroll
        for (int i = 0; i < 4; ++i) {
            const float y = rowbuf[col][m * 8 + 4 * e4 + i] * sc;
            const __hip_fp8_e4m3 f8(y);
            w |= ((unsigned int)f8.__x) << (8 * i);
        }
        dst32[u] = w;
    }
}

// ---------------------------------------------------------------------------
// Kernel 2: L2-traffic-minimized main. R21 A/B showed mainB (no spills) is
// L2-BW-bound: B re-read by all 64 row-blocks = 128MB + 32MB redundant A.
// New: block = 4 waves x (each wave OWNS rb = rbq*4+w, 32 rows) over 256
// cols (8 cg). B staged once per block into LDS (8KB/cg, double-buffered
// via global_load_lds; stage of cg+1 overlaps compute of cg; 1 barrier/cg).
// Traffic: B 32MB + A 8MB -> ~1.5us L2 floor. ~100 VGPR, no spills.
// grid (16,8,4) = 512 blocks = 2/CU, LDS 17.4KB.
// ---------------------------------------------------------------------------
__global__ __launch_bounds__(256, 2) void nnclr_main(const unsigned char* __restrict__ pq2,
                                                     float* __restrict__ sPart,  // [4][2048][8]
                                                     float* __restrict__ dPart)  // [4][2048][8]
{
    const int rbq = blockIdx.x, ch = blockIdx.y, pair = blockIdx.z;
    const int pi = pair >> 1, pj = pair & 1;
    const int tid = threadIdx.x, lane = tid & 63, wave = tid >> 6;
    const int cl = lane & 31, hk = lane >> 5;
    const int rbW = rbq * 4 + wave;                     // this wave's 32-row block

    __shared__ __align__(16) unsigned char bbuf[2][8192];   // double-buffered B cg
    __shared__ float sArr[4][32];
    __shared__ float dArr[4][32];

    const fp8x8* P = (const fp8x8*)pq2;
    // A fragments for this wave's rows (L2, 16 loads, 8KB/wave)
    frag32 aF[4];
    #pragma unroll
    for (int kb = 0; kb < 4; ++kb)
        #pragma unroll
        for (int q = 0; q < 4; ++q)
            aF[kb].g[q] = P[((pi * 64 + rbW) * 32 + 8 * kb + 4 * hk + q) * 32 + cl];

    float sAcc[16];
    #pragma unroll
    for (int r = 0; r < 16; ++r) sAcc[r] = 0.f;
    float d0 = 0.f;
    const int  rDiag    = (cl & 3) + 4 * (cl >> 3);
    const bool laneDiag = (((cl >> 2) & 1) == hk);

    const unsigned char* Bbytes = pq2 + (size_t)(2 + pj) * 524288;   // v-base

    // stage cg chunk c into buffer buf (8KB, 2 x 16B per thread, linear dest)
    #define STAGE(buf, c)                                                          \
        {                                                                          \
            const unsigned char* src_ = Bbytes + ((size_t)(ch * 8 + (c))) * 8192;  \
            _Pragma("unroll")                                                      \
            for (int l = 0; l < 2; ++l) {                                          \
                const int off = l * 4096 + tid * 16;                               \
                __builtin_amdgcn_global_load_lds(                                  \
                    (const __attribute__((address_space(1))) unsigned int*)(src_ + off), \
                    (__attribute__((address_space(3))) unsigned int*)(&bbuf[buf][0] + off), \
                    16, 0, 0);                                                     \
            }                                                                      \
        }

    STAGE(0, 0);
    __syncthreads();                                    // buf0 ready

    #pragma unroll
    for (int c = 0; c < 8; ++c) {
        if (c < 7) STAGE((c + 1) & 1, c + 1);           // overlap next stage
        const fp8x8* L = (const fp8x8*)&bbuf[c & 1][0];
        frag32 bf[4];
        #pragma unroll
        for (int kb = 0; kb < 4; ++kb)
            #pragma unroll
            for (int q = 0; q < 4; ++q)
                bf[kb].g[q] = L[(8 * kb + 4 * hk + q) * 32 + cl];
        f32x16 acc;
        #pragma unroll
        for (int r = 0; r < 16; ++r) acc[r] = 0.f;
        #pragma unroll
        for (int kb = 0; kb < 4; ++kb)
            acc = __builtin_amdgcn_mfma_scale_f32_32x32x64_f8f6f4(
                      aF[kb].v, bf[kb].v, acc, 0, 0, 0, SCALE1, 0, SCALE1);
        // fixed-max (m=5) sum-of-exp + diag pick (static indexing)
        const int cg = ch * 8 + c;
        const bool diagCG = (cg == rbW);                // wave-uniform
        #pragma unroll
        for (int r = 0; r < 16; ++r) {
            const float v0 = acc[r];
            sAcc[r] += __expf(v0 - 5.0f);
            if (diagCG) {
                const bool m = laneDiag && (r == rDiag);
                d0 += m ? v0 : 0.f;
            }
        }
        __syncthreads();   // next buf staged (vmcnt drain) + this buf free
    }

    // per-row col-sum within each hk half
    #pragma unroll
    for (int r = 0; r < 16; ++r) {
        float s0 = sAcc[r];
        #pragma unroll
        for (int msk = 1; msk < 32; msk <<= 1) s0 += __shfl_xor(s0, msk, 64);
        sAcc[r] = s0;
    }
    if (cl == 0) {
        #pragma unroll
        for (int r = 0; r < 16; ++r) {
            const int rowl = (r & 3) + 8 * (r >> 2) + 4 * hk;
            sArr[wave][rowl] = sAcc[r];
        }
    }
    if (laneDiag) dArr[wave][cl] = d0;
    __syncthreads();
    if (tid < 128) {
        const int w = tid >> 5, row = tid & 31;
        const int b = (rbq * 4 + w) * 32 + row;
        sPart[((size_t)pair * TB + b) * 8 + ch] = sArr[w][row];
        dPart[((size_t)pair * TB + b) * 8 + ch] = dArr[w][row];
    }
    #undef STAGE
}

// ---------------------------------------------------------------------------
// Kernel 3: merged final — now 8 chunks per (pair,row). 1 block x 1024 thr.
// ---------------------------------------------------------------------------
__global__ __launch_bounds__(1024) void nnclr_final(const float* __restrict__ sPart,
                                                    const float* __restrict__ dPart,
                                                    float* __restrict__ out) {
    const int tid = threadIdx.x;
    float acc[4] = {0.f, 0.f, 0.f, 0.f};
    #pragma unroll
    for (int k = 0; k < 8; ++k) {
        const int item = k * 1024 + tid;                // pair*2048 + row ; pair = k>>1
        const float4 s0 = ((const float4*)sPart)[item * 2];
        const float4 s1 = ((const float4*)sPart)[item * 2 + 1];
        const float4 e0 = ((const float4*)dPart)[item * 2];
        const float4 e1 = ((const float4*)dPart)[item * 2 + 1];
        const float s = ((s0.x + s0.y) + (s0.z + s0.w)) + ((s1.x + s1.y) + (s1.z + s1.w));
        const float d = ((e0.x + e0.y) + (e0.z + e0.w)) + ((e1.x + e1.y) + (e1.z + e1.w));
        acc[k >> 1] += 5.0f + logf(s) - d;
    }
    __shared__ float red[16][4];
    const int lane = tid & 63, wave = tid >> 6;
    #pragma unroll
    for (int p = 0; p < 4; ++p) {
        #pragma unroll
        for (int m = 1; m < 64; m <<= 1) acc[p] += __shfl_xor(acc[p], m, 64);
    }
    if (lane == 0) {
        #pragma unroll
        for (int p = 0; p < 4; ++p) red[wave][p] = acc[p];
    }
    __syncthreads();
    if (tid == 0) {
        float L[4];
        #pragma unroll
        for (int p = 0; p < 4; ++p) {
            float a = 0.f;
            for (int w = 0; w < 16; ++w) a += red[w][p];
            L[p] = a / (float)TB;
        }
        const float gs = L[1] + L[2];                 // L[0][1] + L[1][0]
        const float ls = L[0] + L[1] + L[2] + L[3];   // all four (Vl==Vg==2)
        out[0] = (gs + ls) / 6.0f;
        out[1] = gs * 0.5f;
        out[2] = ls * 0.25f;
    }
}

extern "C" void kernel_launch(void* const* d_in, const int* in_sizes, int n_in,
                              void* d_out, int out_size, void* d_ws, size_t ws_size,
                              hipStream_t stream) {
    const float* projected = (const float*)d_in[0];   // [2048][2][256] f32
    const float* predicted = (const float*)d_in[1];   // [2048][4][256] f32

    unsigned char* pq2 = (unsigned char*)d_ws;                          // 2 MB fp8, fragment-ordered
    float* sPart = (float*)((char*)d_ws + 4u * 1024u * 1024u);          // 256 KB [4][2048][8]
    float* dPart = sPart + (size_t)4 * TB * 8;                          // 256 KB
    float* out = (float*)d_out;

    dim3 gprep(64, 4);
    nnclr_prep<<<gprep, 256, 0, stream>>>(projected, predicted, pq2);
    dim3 gmain(16, 8, 4);
    nnclr_main<<<gmain, 256, 0, stream>>>(pq2, sPart, dPart);
    nnclr_final<<<1, 1024, 0, stream>>>(sPart, dPart, out);
}